// Round 2
// baseline (392.464 us; speedup 1.0000x reference)
//
#include <hip/hip_runtime.h>
#include <cstdint>

#define B_SZ 8192
#define D_SZ 1024
#define E_SZ 16
#define H_SZ 1024
#define MAXTILES 272   // >= sum_e ceil(count_e/256) worst case (256+16)

using short8 = __attribute__((ext_vector_type(8))) short;
using f32x4  = __attribute__((ext_vector_type(4))) float;

__device__ __forceinline__ unsigned short f2bf(float f) {
  union { float f; unsigned int u; } v; v.f = f;
  unsigned int u = v.u;
  return (unsigned short)((u + 0x7fffu + ((u >> 16) & 1u)) >> 16);  // RNE
}
__device__ __forceinline__ float bf2f(unsigned short h) {
  union { unsigned int u; float f; } v; v.u = ((unsigned int)h) << 16; return v.f;
}

__device__ __forceinline__ void async_ld16(void* lds, const void* g) {
  __builtin_amdgcn_global_load_lds(
      reinterpret_cast<const unsigned int __attribute__((address_space(1)))*>(
          reinterpret_cast<uintptr_t>(g)),
      reinterpret_cast<unsigned int __attribute__((address_space(3)))*>(
          reinterpret_cast<uintptr_t>(lds)),
      16, 0, 0);
}

// ============ prep: fused gating_logits + xcast + wtconv ============
// blocks [0,256): gating_logits; [256,4352): xcast; [4352,8448): wtconv
__global__ __launch_bounds__(256) void prep(
    const float* __restrict__ x, const float* __restrict__ wg,
    const float* __restrict__ wn, const float* __restrict__ ew,
    unsigned short* __restrict__ xb, unsigned short* __restrict__ wtb,
    float* __restrict__ cl, float* __restrict__ rn, float* __restrict__ stats) {
  __shared__ __align__(16) float psm[2 * 32 * 132];   // sx[32][132] + swT[32][132]
  const int bx = blockIdx.x;
  const int tid = threadIdx.x;

  if (bx < 256) {
    float* sx  = psm;              // [row][d] stride 132
    float* swT = psm + 32 * 132;   // [c][d]   stride 132 (c<16: wg, c>=16: wn)
    const int lane = tid & 63;
    const int wave = tid >> 6;
    const int row  = lane & 31;
    const int half = lane >> 5;          // d-half within chunk
    const int rowbase = bx * 32;
    float acc[8] = {0.f, 0.f, 0.f, 0.f, 0.f, 0.f, 0.f, 0.f};

    const int srow = tid >> 3;           // x staging: 32 floats/row/thread-group
    const int sd   = (tid & 7) * 16;
    const int wd   = tid >> 1;           // w staging: d row, 16 cols
    const int wc   = (tid & 1) * 16;
    const float* wsrc = (wc == 0) ? wg : wn;

    for (int ch = 0; ch < 8; ++ch) {
      __syncthreads();
      // stage x chunk: 32 rows x 128 d
      #pragma unroll
      for (int k = 0; k < 4; ++k) {
        const float4 v = *(const float4*)(
            x + (size_t)(rowbase + srow) * D_SZ + ch * 128 + sd + k * 4);
        *(float4*)&sx[srow * 132 + sd + k * 4] = v;
      }
      // stage w chunk transposed: swT[c][d] for c in [wc, wc+16)
      {
        const float* wp = wsrc + (size_t)(ch * 128 + wd) * 16;
        float wv[16];
        #pragma unroll
        for (int k = 0; k < 4; ++k)
          *(float4*)&wv[k * 4] = *(const float4*)(wp + k * 4);
        #pragma unroll
        for (int j = 0; j < 16; ++j) swT[(wc + j) * 132 + wd] = wv[j];
      }
      __syncthreads();
      // compute: each lane: its row, its d-half (64 d), 8 cols (wave*8..+7)
      #pragma unroll 4
      for (int dg = 0; dg < 16; ++dg) {
        const int d = half * 64 + dg * 4;
        const f32x4 xv = *(const f32x4*)&sx[row * 132 + d];
        #pragma unroll
        for (int c = 0; c < 8; ++c) {
          const f32x4 wv = *(const f32x4*)&swT[(wave * 8 + c) * 132 + d];
          acc[c] = fmaf(xv[0], wv[0], acc[c]);
          acc[c] = fmaf(xv[1], wv[1], acc[c]);
          acc[c] = fmaf(xv[2], wv[2], acc[c]);
          acc[c] = fmaf(xv[3], wv[3], acc[c]);
        }
      }
    }
    // combine the two d-halves (lane r += lane r+32)
    #pragma unroll
    for (int c = 0; c < 8; ++c) acc[c] += __shfl_down(acc[c], 32);
    if (lane < 32) {
      const int cg = wave * 8;       // global col 0..31
      float* dst = (cg < 16) ? (cl + (size_t)(rowbase + row) * 16 + cg)
                             : (rn + (size_t)(rowbase + row) * 16 + (cg - 16));
      *(float4*)dst = *(const float4*)&acc[0];
      *(float4*)(dst + 4) = *(const float4*)&acc[4];
    }
  } else if (bx < 4352) {
    // ---- xcast: fp32 -> bf16, 8 floats/thread ----
    const int b = bx - 256;
    const size_t i = (size_t)b * 256 + tid;   // short8 index
    const float4 v0 = ((const float4*)x)[2 * i];
    const float4 v1 = ((const float4*)x)[2 * i + 1];
    unsigned short r[8] = {f2bf(v0.x), f2bf(v0.y), f2bf(v0.z), f2bf(v0.w),
                           f2bf(v1.x), f2bf(v1.y), f2bf(v1.z), f2bf(v1.w)};
    ((short8*)xb)[i] = *(const short8*)r;
    if (b == 0 && tid < 48) stats[tid] = 0.0f;
  } else {
    // ---- wtconv: expert_w (E,D,H) fp32 -> Wt (E,H,D) bf16, vectorized ----
    float (*t)[65] = (float(*)[65])psm;
    const int b = bx - 4352;
    const int e  = b >> 8;
    const int d0 = ((b >> 4) & 15) * 64;
    const int h0 = (b & 15) * 64;
    const float* We = ew + (size_t)e * D_SZ * H_SZ;
    unsigned short* Wte = wtb + (size_t)e * D_SZ * H_SZ;
    #pragma unroll
    for (int i = 0; i < 4; ++i) {
      const int idx = i * 256 + tid;
      const int r = idx >> 4, co = (idx & 15) * 4;
      *(float4*)&t[r][co] =
          *(const float4*)(We + (size_t)(d0 + r) * H_SZ + h0 + co);
    }
    __syncthreads();
    #pragma unroll
    for (int i = 0; i < 2; ++i) {
      const int idx = i * 256 + tid;
      const int r = idx >> 3, c8 = (idx & 7) * 8;
      unsigned short v[8];
      #pragma unroll
      for (int j = 0; j < 8; ++j) v[j] = f2bf(t[c8 + j][r]);
      *(short8*)(Wte + (size_t)(h0 + r) * D_SZ + d0 + c8) = *(const short8*)v;
    }
  }
}

// ---------------- per-row gating: softmax, top-9, gates, load/importance, lists ----
__global__ __launch_bounds__(64) void gating_post(
    const float* __restrict__ clg, const float* __restrict__ rng,
    const float* __restrict__ noise, float* __restrict__ gates,
    float* __restrict__ stats, int* __restrict__ rowidx, int* __restrict__ rowmap) {
  int* gcount = (int*)(stats + 32);
  __shared__ int lcnt[16];
  __shared__ int lbase[16];
  const int row = blockIdx.x * 64 + threadIdx.x;
  if (threadIdx.x < 16) lcnt[threadIdx.x] = 0;
  float cl[16], sd[16], nl[16], p[16];
  #pragma unroll
  for (int e = 0; e < 16; ++e) {
    cl[e] = clg[(size_t)row * 16 + e];
    const float r = rng[(size_t)row * 16 + e];
    sd[e] = fmaxf(r, 0.0f) + log1pf(expf(-fabsf(r))) + 0.01f;  // softplus + eps
    nl[e] = cl[e] + noise[(size_t)row * 16 + e] * sd[e];
  }
  float mx = nl[0];
  #pragma unroll
  for (int e = 1; e < 16; ++e) mx = fmaxf(mx, nl[e]);
  float sum = 0.0f;
  #pragma unroll
  for (int e = 0; e < 16; ++e) { p[e] = expf(nl[e] - mx); sum += p[e]; }
  const float inv = 1.0f / sum;
  #pragma unroll
  for (int e = 0; e < 16; ++e) p[e] *= inv;
  float tmp[16];
  #pragma unroll
  for (int e = 0; e < 16; ++e) tmp[e] = p[e];
  float tv[9]; int ti[9];
  for (int k = 0; k < 9; ++k) {
    float bv = tmp[0]; int bj = 0;
    #pragma unroll
    for (int j = 1; j < 16; ++j) if (tmp[j] > bv) { bv = tmp[j]; bj = j; }
    tv[k] = bv; ti[k] = bj; tmp[bj] = -1.0f;
  }
  float s8 = 0.0f;
  #pragma unroll
  for (int k = 0; k < 8; ++k) s8 += tv[k];
  const float denom = s8 + 1e-6f;
  float g[16];
  #pragma unroll
  for (int e = 0; e < 16; ++e) g[e] = 0.0f;
  for (int k = 0; k < 8; ++k) g[ti[k]] = tv[k] / denom;
  const float thr_in = tv[8], thr_out = tv[7];
  float lc[16];
  #pragma unroll
  for (int e = 0; e < 16; ++e) {
    const float t = (nl[e] > thr_in) ? thr_in : thr_out;
    lc[e] = 0.5f * (1.0f + erff(((cl[e] - t) / sd[e]) * 0.70710678118654752f));
  }
  #pragma unroll
  for (int e = 0; e < 16; ++e) gates[(size_t)row * 16 + e] = g[e];
  __syncthreads();
  int myslot[8];
  #pragma unroll
  for (int k = 0; k < 8; ++k) myslot[k] = atomicAdd(&lcnt[ti[k]], 1);
  __syncthreads();
  if (threadIdx.x < 16) lbase[threadIdx.x] = atomicAdd(&gcount[threadIdx.x], lcnt[threadIdx.x]);
  __syncthreads();
  #pragma unroll
  for (int k = 0; k < 8; ++k) {
    const int e = ti[k];
    const int slot = lbase[e] + myslot[k];
    rowidx[e * B_SZ + slot] = row;
    rowmap[row * 8 + k] = (e << 13) | slot;
  }
  #pragma unroll
  for (int e = 0; e < 16; ++e) {
    float vi = g[e], vl = lc[e];
    for (int o = 32; o > 0; o >>= 1) { vi += __shfl_down(vi, o); vl += __shfl_down(vl, o); }
    if (threadIdx.x == 0) {
      atomicAdd(&stats[e], vi);
      atomicAdd(&stats[16 + e], vl);
    }
  }
}

// ---------------- sparse gather GEMM, 256x256 tile, BK=64, 8 waves -----------------
// m201-style 4-phase K-tile: phase p = {2 x global_load_lds, 4(+8) ds_read_b128,
// barrier, lgkmcnt(0), 16 MFMA (setprio), barrier}. Counted vmcnt(6) once per
// K-tile; never drains to 0 in steady state. Stage/read retirement schedule:
//  during kt: p0: A1,A3(kt+1) [idle buf]   p1: B0,B1(kt+2) [B retired @p0-bar]
//             p2: B2,B3(kt+2)              p3: A0,A2(kt+2) [rows retired @p1-bar]
//  boundary vmcnt(6) confirms all 8 stages of kt+1; 6 of kt+2 remain in flight.
__global__ __launch_bounds__(512, 2) void moe_gemm(
    const unsigned short* __restrict__ Xb,   // [B][D] bf16
    const unsigned short* __restrict__ Wt,   // [E][H][D] bf16
    const float* __restrict__ gates,         // [B][E]
    const float* __restrict__ ebias,         // [E][H]
    const float* __restrict__ stats,         // counts at +32
    const int* __restrict__ rowidx,          // [E][B]
    unsigned short* __restrict__ partial) {  // [padded slots][H] bf16
  // LDS: A bufs [2][256rows][64K] @0..64K, B bufs @64K..128K, sRI/sGG above
  __shared__ __align__(16) char smem[133120];
  int*   sRI = (int*)(smem + 131072);
  float* sGG = (float*)(smem + 132096);

  // ---- self-scan: find (expert, tile) for this block ----
  const int* gcount = (const int*)(stats + 32);
  int my_e = -1, tile = 0, tstart = 0, acc_t = 0;
  #pragma unroll
  for (int ee = 0; ee < 16; ++ee) {
    const int nt_e = (gcount[ee] + 255) >> 8;
    if (my_e < 0 && (int)blockIdx.y < acc_t + nt_e) {
      my_e = ee; tile = (int)blockIdx.y - acc_t; tstart = acc_t;
    }
    acc_t += nt_e;
  }
  if (my_e < 0) return;
  const int e = my_e;
  const int slot0 = tile << 8;
  const int cnt = gcount[e];
  const int col0 = (int)blockIdx.x << 8;

  const int tid  = (int)threadIdx.x;
  const int lane = tid & 63;
  const int wave = tid >> 6;
  const int wm = wave >> 2, wn = wave & 3;   // 2 x 4 waves; per-wave out 128x64
  const int ml = lane & 15;
  const int quad = lane >> 4;
  const int wb = tid & ~63;                  // wave-uniform chunk base

  if (tid < 256) {
    const int slot = slot0 + tid;
    const int ok = slot < cnt;
    const int row = ok ? rowidx[e * B_SZ + slot] : 0;
    sRI[tid] = row;
    sGG[tid] = ok ? gates[(size_t)row * 16 + e] : 0.0f;
  }
  __syncthreads();

  // per-thread staging sources (pre-swizzled K-chunk; LDS dest stays linear)
  const int gc = (tid & 7) ^ ((tid >> 3) & 7);
  const int rl = tid >> 3;                   // row within 64-row load slot
  const unsigned short* const We = Wt + (size_t)e * D_SZ * H_SZ;
  const unsigned short* a_src0 = Xb + (size_t)sRI[rl]       * D_SZ + gc * 8;
  const unsigned short* a_src1 = Xb + (size_t)sRI[64 + rl]  * D_SZ + gc * 8;
  const unsigned short* a_src2 = Xb + (size_t)sRI[128 + rl] * D_SZ + gc * 8;
  const unsigned short* a_src3 = Xb + (size_t)sRI[192 + rl] * D_SZ + gc * 8;
  const unsigned short* b_src0 = We + (size_t)(col0 + rl)   * D_SZ + gc * 8;

#define STG_A(kt, l) \
  async_ld16(smem + (((kt) & 1) * 32768) + ((((l) * 512 + wb)) << 4), \
             a_src##l + (kt) * 64)
#define STG_B(kt, l) \
  async_ld16(smem + 65536 + (((kt) & 1) * 32768) + ((((l) * 512 + wb)) << 4), \
             b_src0 + (l) * 65536 + (kt) * 64)

  // ---- prologue: kt0 complete (order A0,A2,B*,A1,A3) + kt1's A0,A2,B* ----
  STG_A(0,0); STG_A(0,2);
  STG_B(0,0); STG_B(0,1); STG_B(0,2); STG_B(0,3);
  STG_A(0,1); STG_A(0,3);
  STG_A(1,0); STG_A(1,2);
  STG_B(1,0); STG_B(1,1); STG_B(1,2); STG_B(1,3);
  asm volatile("s_waitcnt vmcnt(6)" ::: "memory");   // kt0's 8 stages complete
  __builtin_amdgcn_s_barrier();

  f32x4 acc[8][4] = {};

#define RD_B() \
  do { _Pragma("unroll") for (int j = 0; j < 4; ++j) { \
    const int n = wn * 64 + j * 16 + ml; \
    _Pragma("unroll") for (int kk = 0; kk < 2; ++kk) { \
      const int c = (kk * 4 + quad) ^ (n & 7); \
      bf[j][kk] = *(const short8*)(sBb + (size_t)(n * 8 + c) * 8); \
    } } } while (0)

#define RD_A(p) \
  do { _Pragma("unroll") for (int ii = 0; ii < 2; ++ii) { \
    const int m = wm * 128 + ((p) * 2 + ii) * 16 + ml; \
    _Pragma("unroll") for (int kk = 0; kk < 2; ++kk) { \
      const int c = (kk * 4 + quad) ^ (m & 7); \
      af[ii][kk] = *(const short8*)(sAb + (size_t)(m * 8 + c) * 8); \
    } } } while (0)

#define WAIT_LGKM0() \
  do { asm volatile("s_waitcnt lgkmcnt(0)" ::: "memory"); \
       __builtin_amdgcn_sched_barrier(0); } while (0)

#define MFP(p) \
  do { __builtin_amdgcn_s_setprio(1); \
    _Pragma("unroll") for (int ii = 0; ii < 2; ++ii) \
      _Pragma("unroll") for (int j = 0; j < 4; ++j) \
        _Pragma("unroll") for (int kk = 0; kk < 2; ++kk) \
          acc[(p) * 2 + ii][j] = __builtin_amdgcn_mfma_f32_16x16x32_bf16( \
              af[ii][kk], bf[j][kk], acc[(p) * 2 + ii][j], 0, 0, 0); \
    __builtin_amdgcn_s_setprio(0); } while (0)

  #pragma unroll
  for (int kt = 0; kt < 16; ++kt) {
    const unsigned short* sAb =
        (const unsigned short*)(smem + ((kt & 1) ? 32768 : 0));
    const unsigned short* sBb =
        (const unsigned short*)(smem + 65536 + ((kt & 1) ? 32768 : 0));
    short8 af[2][2], bf[4][2];
    // ---- phase 0: stage kt+1's late A halves; read af01 + ALL bf ----
    if (kt + 1 < 16) { STG_A(kt + 1, 1); STG_A(kt + 1, 3); }
    RD_A(0); RD_B();
    __builtin_amdgcn_s_barrier();
    WAIT_LGKM0();
    MFP(0);
    __builtin_amdgcn_s_barrier();          // all waves' bf reads retired
    // ---- phase 1: stage kt+2 B0,B1 (B region retired); read af23 ----
    if (kt + 2 < 16) { STG_B(kt + 2, 0); STG_B(kt + 2, 1); }
    RD_A(1);
    __builtin_amdgcn_s_barrier();
    WAIT_LGKM0();
    MFP(1);
    __builtin_amdgcn_s_barrier();          // A rows 0-63/128-191 retired
    // ---- phase 2: stage kt+2 B2,B3; read af45 ----
    if (kt + 2 < 16) { STG_B(kt + 2, 2); STG_B(kt + 2, 3); }
    RD_A(2);
    __builtin_amdgcn_s_barrier();
    WAIT_LGKM0();
    MFP(2);
    __builtin_amdgcn_s_barrier();
    // ---- phase 3: stage kt+2 A0,A2 (those rows retired @p1-bar); read af67 ----
    if (kt + 2 < 16) { STG_A(kt + 2, 0); STG_A(kt + 2, 2); }
    RD_A(3);
    __builtin_amdgcn_s_barrier();
    WAIT_LGKM0();
    MFP(3);
    // ---- K-tile boundary: confirm all 8 stages of kt+1; keep 6 in flight ----
    if (kt <= 13) {
      asm volatile("s_waitcnt vmcnt(6)" ::: "memory");
    } else if (kt == 14) {
      asm volatile("s_waitcnt vmcnt(0)" ::: "memory");
    }
    __builtin_amdgcn_s_barrier();
  }
#undef MFP
#undef WAIT_LGKM0
#undef RD_A
#undef RD_B
#undef STG_A
#undef STG_B

  // ---- epilogue: gate*(acc+bias) -> LDS (stride 264) -> full-line nt stores ----
  __syncthreads();
  float ebv[4];
  #pragma unroll
  for (int j = 0; j < 4; ++j)
    ebv[j] = ebias[(size_t)e * H_SZ + col0 + wn * 64 + j * 16 + ml];
  unsigned short* sOut = (unsigned short*)smem;
  const size_t prow0 = (size_t)((tstart << 8) + slot0);
  #pragma unroll
  for (int half = 0; half < 2; ++half) {
    if (wm == half) {
      #pragma unroll
      for (int i = 0; i < 8; ++i) {
        const int lr = i * 16 + quad * 4;
        #pragma unroll
        for (int r = 0; r < 4; ++r) {
          const float gv = sGG[half * 128 + lr + r];
          #pragma unroll
          for (int j = 0; j < 4; ++j) {
            const int cc = wn * 64 + j * 16 + ml;
            sOut[(lr + r) * 264 + cc] = f2bf(gv * (acc[i][j][r] + ebv[j]));
          }
        }
      }
    }
    __syncthreads();
    #pragma unroll
    for (int it = 0; it < 8; ++it) {
      const int s = it * 512 + tid;
      const int rr = s >> 5;
      const int c8 = (s & 31) * 8;
      const short8 v = *(const short8*)(sOut + rr * 264 + c8);
      __builtin_nontemporal_store(
          v, (short8*)(partial + (prow0 + half * 128 + rr) * H_SZ + col0 + c8));
    }
    __syncthreads();
  }
}

// ---------------- per-row reduce of 8 partials (+ loss finalize) ----------
// 4 rows/block, 2048 blocks; thread = (row r=tid>>6, 16-short seg (tid&63)*16)
__global__ __launch_bounds__(256) void reduce_k(
    const unsigned short* __restrict__ partial, const int* __restrict__ rowmap,
    const float* __restrict__ stats, float* __restrict__ y) {
  const int row0 = blockIdx.x * 4;
  const int tid = threadIdx.x;
  const int* gcount = (const int*)(stats + 32);
  __shared__ int sp[4][8];
  if (tid < 32) {
    const int r = tid >> 3, k = tid & 7;
    const int v = rowmap[(row0 + r) * 8 + k];
    const int e = v >> 13, slot = v & 8191;
    int t = 0;
    #pragma unroll
    for (int ee = 0; ee < 16; ++ee) t += (ee < e) ? ((gcount[ee] + 255) >> 8) : 0;
    sp[r][k] = (t << 8) + slot;
  }
  __syncthreads();
  const int r = tid >> 6;
  const int c0 = (tid & 63) * 16;
  float a[16];
  #pragma unroll
  for (int j = 0; j < 16; ++j) a[j] = 0.f;
  #pragma unroll
  for (int k = 0; k < 8; ++k) {
    const unsigned short* pp = partial + (size_t)sp[r][k] * H_SZ + c0;
    const short8 p0 = *(const short8*)pp;
    const short8 p1 = *(const short8*)(pp + 8);
    #pragma unroll
    for (int j = 0; j < 8; ++j) {
      a[j]     += bf2f((unsigned short)p0[j]);
      a[j + 8] += bf2f((unsigned short)p1[j]);
    }
  }
  float* yp = y + (size_t)(row0 + r) * H_SZ + c0;
  #pragma unroll
  for (int q = 0; q < 4; ++q) {
    float4 o = {a[q * 4], a[q * 4 + 1], a[q * 4 + 2], a[q * 4 + 3]};
    *(float4*)(yp + q * 4) = o;
  }

  // ---- loss finalize (one thread of one block) ----
  if (blockIdx.x == 0 && tid == 0) {
    double si = 0.0, sl = 0.0;
    for (int e = 0; e < 16; ++e) { si += stats[e]; sl += stats[16 + e]; }
    const double mi = si / 16.0, mld = sl / 16.0;
    double vi = 0.0, vl = 0.0;
    for (int e = 0; e < 16; ++e) {
      const double di = stats[e] - mi;       vi += di * di;
      const double dl = stats[16 + e] - mld; vl += dl * dl;
    }
    vi /= 15.0; vl /= 15.0;  // ddof=1
    const double loss = 0.01 * (vi / (mi * mi + 1e-10) + vl / (mld * mld + 1e-10));
    y[(size_t)B_SZ * H_SZ] = (float)loss;
  }
}

extern "C" void kernel_launch(void* const* d_in, const int* in_sizes, int n_in,
                              void* d_out, int out_size, void* d_ws, size_t ws_size,
                              hipStream_t stream) {
  (void)in_sizes; (void)n_in; (void)out_size; (void)ws_size;
  const float* x    = (const float*)d_in[0];
  const float* wg   = (const float*)d_in[1];
  const float* wnoi = (const float*)d_in[2];
  const float* ew   = (const float*)d_in[3];
  const float* eb   = (const float*)d_in[4];
  const float* nz   = (const float*)d_in[5];
  float* y = (float*)d_out;

  char* ws = (char*)d_ws;
  const size_t MB = 1024 * 1024;
  unsigned short* xb     = (unsigned short*)(ws);                 // 16 MB
  unsigned short* wtb    = (unsigned short*)(ws + 16 * MB);       // 32 MB
  float* cl              = (float*)(ws + 48 * MB);                // 512 KB
  float* rn              = (float*)(ws + 48 * MB + 512 * 1024);   // 512 KB
  float* gates           = (float*)(ws + 49 * MB);                // 512 KB
  int*   rowidx          = (int*)  (ws + 49 * MB + 512 * 1024);   // 512 KB
  int*   rowmap          = (int*)  (ws + 50 * MB);                // 256 KB
  float* stats           = (float*)(ws + 50 * MB + 512 * 1024);   // 32 f32 + 16 counts
  unsigned short* partial= (unsigned short*)(ws + 52 * MB);       // ~143 MB

  hipLaunchKernelGGL(prep,        dim3(8448),         dim3(256), 0, stream,
                     x, wg, wnoi, ew, xb, wtb, cl, rn, stats);
  hipLaunchKernelGGL(gating_post, dim3(128),          dim3(64),  0, stream,
                     cl, rn, nz, gates, stats, rowidx, rowmap);
  hipLaunchKernelGGL(moe_gemm,    dim3(4, MAXTILES),  dim3(512), 0, stream,
                     xb, wtb, gates, eb, stats, rowidx, partial);
  hipLaunchKernelGGL(reduce_k,    dim3(2048),         dim3(256), 0, stream,
                     partial, rowmap, stats, y);
}

// Round 3
// 388.987 us; speedup vs baseline: 1.0089x; 1.0089x over previous
//
#include <hip/hip_runtime.h>
#include <cstdint>

#define B_SZ 8192
#define D_SZ 1024
#define E_SZ 16
#define H_SZ 1024
#define MAXTILES 272   // >= sum_e ceil(count_e/256) worst case (256+16)

using short8 = __attribute__((ext_vector_type(8))) short;
using f32x4  = __attribute__((ext_vector_type(4))) float;

__device__ __forceinline__ unsigned short f2bf(float f) {
  union { float f; unsigned int u; } v; v.f = f;
  unsigned int u = v.u;
  return (unsigned short)((u + 0x7fffu + ((u >> 16) & 1u)) >> 16);  // RNE
}
__device__ __forceinline__ float bf2f(unsigned short h) {
  union { unsigned int u; float f; } v; v.u = ((unsigned int)h) << 16; return v.f;
}

__device__ __forceinline__ void async_ld16(void* lds, const void* g) {
  __builtin_amdgcn_global_load_lds(
      reinterpret_cast<const unsigned int __attribute__((address_space(1)))*>(
          reinterpret_cast<uintptr_t>(g)),
      reinterpret_cast<unsigned int __attribute__((address_space(3)))*>(
          reinterpret_cast<uintptr_t>(lds)),
      16, 0, 0);
}

// ============ prep: fused gating_logits + xcast + wtconv ============
// blocks [0,256): gating_logits; [256,4352): xcast; [4352,8448): wtconv
__global__ __launch_bounds__(256) void prep(
    const float* __restrict__ x, const float* __restrict__ wg,
    const float* __restrict__ wn, const float* __restrict__ ew,
    unsigned short* __restrict__ xb, unsigned short* __restrict__ wtb,
    float* __restrict__ cl, float* __restrict__ rn, float* __restrict__ stats) {
  __shared__ __align__(16) float psm[2 * 32 * 132];   // sx[32][132] + swT[32][132]
  const int bx = blockIdx.x;
  const int tid = threadIdx.x;

  if (bx < 256) {
    float* sx  = psm;              // [row][d] stride 132
    float* swT = psm + 32 * 132;   // [c][d]   stride 132 (c<16: wg, c>=16: wn)
    const int lane = tid & 63;
    const int wave = tid >> 6;
    const int row  = lane & 31;
    const int half = lane >> 5;          // d-half within chunk
    const int rowbase = bx * 32;
    float acc[8] = {0.f, 0.f, 0.f, 0.f, 0.f, 0.f, 0.f, 0.f};

    const int srow = tid >> 3;           // x staging: 32 floats/row/thread-group
    const int sd   = (tid & 7) * 16;
    const int wd   = tid >> 1;           // w staging: d row, 16 cols
    const int wc   = (tid & 1) * 16;
    const float* wsrc = (wc == 0) ? wg : wn;

    for (int ch = 0; ch < 8; ++ch) {
      __syncthreads();
      // stage x chunk: 32 rows x 128 d
      #pragma unroll
      for (int k = 0; k < 4; ++k) {
        const float4 v = *(const float4*)(
            x + (size_t)(rowbase + srow) * D_SZ + ch * 128 + sd + k * 4);
        *(float4*)&sx[srow * 132 + sd + k * 4] = v;
      }
      // stage w chunk transposed: swT[c][d] for c in [wc, wc+16)
      {
        const float* wp = wsrc + (size_t)(ch * 128 + wd) * 16;
        float wv[16];
        #pragma unroll
        for (int k = 0; k < 4; ++k)
          *(float4*)&wv[k * 4] = *(const float4*)(wp + k * 4);
        #pragma unroll
        for (int j = 0; j < 16; ++j) swT[(wc + j) * 132 + wd] = wv[j];
      }
      __syncthreads();
      // compute: each lane: its row, its d-half (64 d), 8 cols (wave*8..+7)
      #pragma unroll 4
      for (int dg = 0; dg < 16; ++dg) {
        const int d = half * 64 + dg * 4;
        const f32x4 xv = *(const f32x4*)&sx[row * 132 + d];
        #pragma unroll
        for (int c = 0; c < 8; ++c) {
          const f32x4 wv = *(const f32x4*)&swT[(wave * 8 + c) * 132 + d];
          acc[c] = fmaf(xv[0], wv[0], acc[c]);
          acc[c] = fmaf(xv[1], wv[1], acc[c]);
          acc[c] = fmaf(xv[2], wv[2], acc[c]);
          acc[c] = fmaf(xv[3], wv[3], acc[c]);
        }
      }
    }
    // combine the two d-halves (lane r += lane r+32)
    #pragma unroll
    for (int c = 0; c < 8; ++c) acc[c] += __shfl_down(acc[c], 32);
    if (lane < 32) {
      const int cg = wave * 8;       // global col 0..31
      float* dst = (cg < 16) ? (cl + (size_t)(rowbase + row) * 16 + cg)
                             : (rn + (size_t)(rowbase + row) * 16 + (cg - 16));
      *(float4*)dst = *(const float4*)&acc[0];
      *(float4*)(dst + 4) = *(const float4*)&acc[4];
    }
  } else if (bx < 4352) {
    // ---- xcast: fp32 -> bf16, 8 floats/thread ----
    const int b = bx - 256;
    const size_t i = (size_t)b * 256 + tid;   // short8 index
    const float4 v0 = ((const float4*)x)[2 * i];
    const float4 v1 = ((const float4*)x)[2 * i + 1];
    unsigned short r[8] = {f2bf(v0.x), f2bf(v0.y), f2bf(v0.z), f2bf(v0.w),
                           f2bf(v1.x), f2bf(v1.y), f2bf(v1.z), f2bf(v1.w)};
    ((short8*)xb)[i] = *(const short8*)r;
    if (b == 0 && tid < 48) stats[tid] = 0.0f;
  } else {
    // ---- wtconv: expert_w (E,D,H) fp32 -> Wt (E,H,D) bf16, vectorized ----
    float (*t)[65] = (float(*)[65])psm;
    const int b = bx - 4352;
    const int e  = b >> 8;
    const int d0 = ((b >> 4) & 15) * 64;
    const int h0 = (b & 15) * 64;
    const float* We = ew + (size_t)e * D_SZ * H_SZ;
    unsigned short* Wte = wtb + (size_t)e * D_SZ * H_SZ;
    #pragma unroll
    for (int i = 0; i < 4; ++i) {
      const int idx = i * 256 + tid;
      const int r = idx >> 4, co = (idx & 15) * 4;
      *(float4*)&t[r][co] =
          *(const float4*)(We + (size_t)(d0 + r) * H_SZ + h0 + co);
    }
    __syncthreads();
    #pragma unroll
    for (int i = 0; i < 2; ++i) {
      const int idx = i * 256 + tid;
      const int r = idx >> 3, c8 = (idx & 7) * 8;
      unsigned short v[8];
      #pragma unroll
      for (int j = 0; j < 8; ++j) v[j] = f2bf(t[c8 + j][r]);
      *(short8*)(Wte + (size_t)(h0 + r) * D_SZ + d0 + c8) = *(const short8*)v;
    }
  }
}

// ---------------- per-row gating: softmax, top-9, gates, load/importance, lists ----
__global__ __launch_bounds__(64) void gating_post(
    const float* __restrict__ clg, const float* __restrict__ rng,
    const float* __restrict__ noise, float* __restrict__ gates,
    float* __restrict__ stats, int* __restrict__ rowidx, int* __restrict__ rowmap) {
  int* gcount = (int*)(stats + 32);
  __shared__ int lcnt[16];
  __shared__ int lbase[16];
  const int row = blockIdx.x * 64 + threadIdx.x;
  if (threadIdx.x < 16) lcnt[threadIdx.x] = 0;
  float cl[16], sd[16], nl[16], p[16];
  #pragma unroll
  for (int e = 0; e < 16; ++e) {
    cl[e] = clg[(size_t)row * 16 + e];
    const float r = rng[(size_t)row * 16 + e];
    sd[e] = fmaxf(r, 0.0f) + log1pf(expf(-fabsf(r))) + 0.01f;  // softplus + eps
    nl[e] = cl[e] + noise[(size_t)row * 16 + e] * sd[e];
  }
  float mx = nl[0];
  #pragma unroll
  for (int e = 1; e < 16; ++e) mx = fmaxf(mx, nl[e]);
  float sum = 0.0f;
  #pragma unroll
  for (int e = 0; e < 16; ++e) { p[e] = expf(nl[e] - mx); sum += p[e]; }
  const float inv = 1.0f / sum;
  #pragma unroll
  for (int e = 0; e < 16; ++e) p[e] *= inv;
  float tmp[16];
  #pragma unroll
  for (int e = 0; e < 16; ++e) tmp[e] = p[e];
  float tv[9]; int ti[9];
  for (int k = 0; k < 9; ++k) {
    float bv = tmp[0]; int bj = 0;
    #pragma unroll
    for (int j = 1; j < 16; ++j) if (tmp[j] > bv) { bv = tmp[j]; bj = j; }
    tv[k] = bv; ti[k] = bj; tmp[bj] = -1.0f;
  }
  float s8 = 0.0f;
  #pragma unroll
  for (int k = 0; k < 8; ++k) s8 += tv[k];
  const float denom = s8 + 1e-6f;
  float g[16];
  #pragma unroll
  for (int e = 0; e < 16; ++e) g[e] = 0.0f;
  for (int k = 0; k < 8; ++k) g[ti[k]] = tv[k] / denom;
  const float thr_in = tv[8], thr_out = tv[7];
  float lc[16];
  #pragma unroll
  for (int e = 0; e < 16; ++e) {
    const float t = (nl[e] > thr_in) ? thr_in : thr_out;
    lc[e] = 0.5f * (1.0f + erff(((cl[e] - t) / sd[e]) * 0.70710678118654752f));
  }
  #pragma unroll
  for (int e = 0; e < 16; ++e) gates[(size_t)row * 16 + e] = g[e];
  __syncthreads();
  int myslot[8];
  #pragma unroll
  for (int k = 0; k < 8; ++k) myslot[k] = atomicAdd(&lcnt[ti[k]], 1);
  __syncthreads();
  if (threadIdx.x < 16) lbase[threadIdx.x] = atomicAdd(&gcount[threadIdx.x], lcnt[threadIdx.x]);
  __syncthreads();
  #pragma unroll
  for (int k = 0; k < 8; ++k) {
    const int e = ti[k];
    const int slot = lbase[e] + myslot[k];
    rowidx[e * B_SZ + slot] = row;
    rowmap[row * 8 + k] = (e << 13) | slot;
  }
  #pragma unroll
  for (int e = 0; e < 16; ++e) {
    float vi = g[e], vl = lc[e];
    for (int o = 32; o > 0; o >>= 1) { vi += __shfl_down(vi, o); vl += __shfl_down(vl, o); }
    if (threadIdx.x == 0) {
      atomicAdd(&stats[e], vi);
      atomicAdd(&stats[16 + e], vl);
    }
  }
}

// ---------------- sparse gather GEMM, 256x256 tile, BK=64, 8 waves -----------------
// 4-phase K-tile, counted vmcnt(6) (see r2 comments).  NEW: XCD-chunked block
// swizzle — 1-D grid 1088 (8*136); logical = (orig&7)*136 + (orig>>3); the 4
// col-siblings of a tile and runs of same-expert tiles share one XCD's L2, so
// A-tiles are fetched once per XCD (not 4x) and B panels stay L2-resident.
__global__ __launch_bounds__(512, 2) void moe_gemm(
    const unsigned short* __restrict__ Xb,   // [B][D] bf16
    const unsigned short* __restrict__ Wt,   // [E][H][D] bf16
    const float* __restrict__ gates,         // [B][E]
    const float* __restrict__ ebias,         // [E][H]
    const float* __restrict__ stats,         // counts at +32
    const int* __restrict__ rowidx,          // [E][B]
    unsigned short* __restrict__ partial) {  // [padded slots][H] bf16
  // LDS: A bufs [2][256rows][64K] @0..64K, B bufs @64K..128K, sRI/sGG above
  __shared__ __align__(16) char smem[133120];
  int*   sRI = (int*)(smem + 131072);
  float* sGG = (float*)(smem + 132096);

  // ---- XCD-chunked swizzle (4*MAXTILES = 1088 = 8*136, exact) ----
  const int orig = (int)blockIdx.x;
  const int logical = (orig & 7) * (4 * MAXTILES / 8) + (orig >> 3);
  const int tileY = logical >> 2;
  const int col  = logical & 3;

  // ---- self-scan: find (expert, tile) for this block ----
  const int* gcount = (const int*)(stats + 32);
  int my_e = -1, tile = 0, tstart = 0, acc_t = 0;
  #pragma unroll
  for (int ee = 0; ee < 16; ++ee) {
    const int nt_e = (gcount[ee] + 255) >> 8;
    if (my_e < 0 && tileY < acc_t + nt_e) {
      my_e = ee; tile = tileY - acc_t; tstart = acc_t;
    }
    acc_t += nt_e;
  }
  if (my_e < 0) return;
  const int e = my_e;
  const int slot0 = tile << 8;
  const int cnt = gcount[e];
  const int col0 = col << 8;

  const int tid  = (int)threadIdx.x;
  const int lane = tid & 63;
  const int wave = tid >> 6;
  const int wm = wave >> 2, wn = wave & 3;   // 2 x 4 waves; per-wave out 128x64
  const int ml = lane & 15;
  const int quad = lane >> 4;
  const int wb = tid & ~63;                  // wave-uniform chunk base

  if (tid < 256) {
    const int slot = slot0 + tid;
    const int ok = slot < cnt;
    const int row = ok ? rowidx[e * B_SZ + slot] : 0;
    sRI[tid] = row;
    sGG[tid] = ok ? gates[(size_t)row * 16 + e] : 0.0f;
  }
  __syncthreads();

  // per-thread staging sources (pre-swizzled K-chunk; LDS dest stays linear)
  const int gc = (tid & 7) ^ ((tid >> 3) & 7);
  const int rl = tid >> 3;                   // row within 64-row load slot
  const unsigned short* const We = Wt + (size_t)e * D_SZ * H_SZ;
  const unsigned short* a_src0 = Xb + (size_t)sRI[rl]       * D_SZ + gc * 8;
  const unsigned short* a_src1 = Xb + (size_t)sRI[64 + rl]  * D_SZ + gc * 8;
  const unsigned short* a_src2 = Xb + (size_t)sRI[128 + rl] * D_SZ + gc * 8;
  const unsigned short* a_src3 = Xb + (size_t)sRI[192 + rl] * D_SZ + gc * 8;
  const unsigned short* b_src0 = We + (size_t)(col0 + rl)   * D_SZ + gc * 8;

#define STG_A(kt, l) \
  async_ld16(smem + (((kt) & 1) * 32768) + ((((l) * 512 + wb)) << 4), \
             a_src##l + (kt) * 64)
#define STG_B(kt, l) \
  async_ld16(smem + 65536 + (((kt) & 1) * 32768) + ((((l) * 512 + wb)) << 4), \
             b_src0 + (l) * 65536 + (kt) * 64)

  // ---- prologue: kt0 complete (order A0,A2,B*,A1,A3) + kt1's A0,A2,B* ----
  STG_A(0,0); STG_A(0,2);
  STG_B(0,0); STG_B(0,1); STG_B(0,2); STG_B(0,3);
  STG_A(0,1); STG_A(0,3);
  STG_A(1,0); STG_A(1,2);
  STG_B(1,0); STG_B(1,1); STG_B(1,2); STG_B(1,3);
  asm volatile("s_waitcnt vmcnt(6)" ::: "memory");   // kt0's 8 stages complete
  __builtin_amdgcn_s_barrier();

  f32x4 acc[8][4] = {};

#define RD_B() \
  do { _Pragma("unroll") for (int j = 0; j < 4; ++j) { \
    const int n = wn * 64 + j * 16 + ml; \
    _Pragma("unroll") for (int kk = 0; kk < 2; ++kk) { \
      const int c = (kk * 4 + quad) ^ (n & 7); \
      bf[j][kk] = *(const short8*)(sBb + (size_t)(n * 8 + c) * 8); \
    } } } while (0)

#define RD_A(p) \
  do { _Pragma("unroll") for (int ii = 0; ii < 2; ++ii) { \
    const int m = wm * 128 + ((p) * 2 + ii) * 16 + ml; \
    _Pragma("unroll") for (int kk = 0; kk < 2; ++kk) { \
      const int c = (kk * 4 + quad) ^ (m & 7); \
      af[ii][kk] = *(const short8*)(sAb + (size_t)(m * 8 + c) * 8); \
    } } } while (0)

#define WAIT_LGKM0() \
  do { asm volatile("s_waitcnt lgkmcnt(0)" ::: "memory"); \
       __builtin_amdgcn_sched_barrier(0); } while (0)

#define MFP(p) \
  do { __builtin_amdgcn_s_setprio(1); \
    _Pragma("unroll") for (int ii = 0; ii < 2; ++ii) \
      _Pragma("unroll") for (int j = 0; j < 4; ++j) \
        _Pragma("unroll") for (int kk = 0; kk < 2; ++kk) \
          acc[(p) * 2 + ii][j] = __builtin_amdgcn_mfma_f32_16x16x32_bf16( \
              af[ii][kk], bf[j][kk], acc[(p) * 2 + ii][j], 0, 0, 0); \
    __builtin_amdgcn_s_setprio(0); } while (0)

  #pragma unroll
  for (int kt = 0; kt < 16; ++kt) {
    const unsigned short* sAb =
        (const unsigned short*)(smem + ((kt & 1) ? 32768 : 0));
    const unsigned short* sBb =
        (const unsigned short*)(smem + 65536 + ((kt & 1) ? 32768 : 0));
    short8 af[2][2], bf[4][2];
    // ---- phase 0: stage kt+1's late A halves; read af01 + ALL bf ----
    if (kt + 1 < 16) { STG_A(kt + 1, 1); STG_A(kt + 1, 3); }
    RD_A(0); RD_B();
    __builtin_amdgcn_s_barrier();
    WAIT_LGKM0();
    MFP(0);
    __builtin_amdgcn_s_barrier();          // all waves' bf reads retired
    // ---- phase 1: stage kt+2 B0,B1 (B region retired); read af23 ----
    if (kt + 2 < 16) { STG_B(kt + 2, 0); STG_B(kt + 2, 1); }
    RD_A(1);
    __builtin_amdgcn_s_barrier();
    WAIT_LGKM0();
    MFP(1);
    __builtin_amdgcn_s_barrier();          // A rows 0-63/128-191 retired
    // ---- phase 2: stage kt+2 B2,B3; read af45 ----
    if (kt + 2 < 16) { STG_B(kt + 2, 2); STG_B(kt + 2, 3); }
    RD_A(2);
    __builtin_amdgcn_s_barrier();
    WAIT_LGKM0();
    MFP(2);
    __builtin_amdgcn_s_barrier();
    // ---- phase 3: stage kt+2 A0,A2 (those rows retired @p1-bar); read af67 ----
    if (kt + 2 < 16) { STG_A(kt + 2, 0); STG_A(kt + 2, 2); }
    RD_A(3);
    __builtin_amdgcn_s_barrier();
    WAIT_LGKM0();
    MFP(3);
    // ---- K-tile boundary: confirm all 8 stages of kt+1; keep 6 in flight ----
    if (kt <= 13) {
      asm volatile("s_waitcnt vmcnt(6)" ::: "memory");
    } else if (kt == 14) {
      asm volatile("s_waitcnt vmcnt(0)" ::: "memory");
    }
    __builtin_amdgcn_s_barrier();
  }
#undef MFP
#undef WAIT_LGKM0
#undef RD_A
#undef RD_B
#undef STG_A
#undef STG_B

  // ---- epilogue: gate*(acc+bias) -> LDS (stride 264) -> full-line nt stores ----
  __syncthreads();
  float ebv[4];
  #pragma unroll
  for (int j = 0; j < 4; ++j)
    ebv[j] = ebias[(size_t)e * H_SZ + col0 + wn * 64 + j * 16 + ml];
  unsigned short* sOut = (unsigned short*)smem;
  const size_t prow0 = (size_t)((tstart << 8) + slot0);
  #pragma unroll
  for (int half = 0; half < 2; ++half) {
    if (wm == half) {
      #pragma unroll
      for (int i = 0; i < 8; ++i) {
        const int lr = i * 16 + quad * 4;
        #pragma unroll
        for (int r = 0; r < 4; ++r) {
          const float gv = sGG[half * 128 + lr + r];
          #pragma unroll
          for (int j = 0; j < 4; ++j) {
            const int cc = wn * 64 + j * 16 + ml;
            sOut[(lr + r) * 264 + cc] = f2bf(gv * (acc[i][j][r] + ebv[j]));
          }
        }
      }
    }
    __syncthreads();
    #pragma unroll
    for (int it = 0; it < 8; ++it) {
      const int s = it * 512 + tid;
      const int rr = s >> 5;
      const int c8 = (s & 31) * 8;
      const short8 v = *(const short8*)(sOut + rr * 264 + c8);
      __builtin_nontemporal_store(
          v, (short8*)(partial + (prow0 + half * 128 + rr) * H_SZ + col0 + c8));
    }
    __syncthreads();
  }
}

// ---------------- per-row reduce of 8 partials (+ loss finalize) ----------
// 4 rows/block, 2048 blocks; thread = (row r=tid>>6, 16-short seg (tid&63)*16)
__global__ __launch_bounds__(256) void reduce_k(
    const unsigned short* __restrict__ partial, const int* __restrict__ rowmap,
    const float* __restrict__ stats, float* __restrict__ y) {
  const int row0 = blockIdx.x * 4;
  const int tid = threadIdx.x;
  const int* gcount = (const int*)(stats + 32);
  __shared__ int sp[4][8];
  if (tid < 32) {
    const int r = tid >> 3, k = tid & 7;
    const int v = rowmap[(row0 + r) * 8 + k];
    const int e = v >> 13, slot = v & 8191;
    int t = 0;
    #pragma unroll
    for (int ee = 0; ee < 16; ++ee) t += (ee < e) ? ((gcount[ee] + 255) >> 8) : 0;
    sp[r][k] = (t << 8) + slot;
  }
  __syncthreads();
  const int r = tid >> 6;
  const int c0 = (tid & 63) * 16;
  float a[16];
  #pragma unroll
  for (int j = 0; j < 16; ++j) a[j] = 0.f;
  #pragma unroll
  for (int k = 0; k < 8; ++k) {
    const unsigned short* pp = partial + (size_t)sp[r][k] * H_SZ + c0;
    const short8 p0 = *(const short8*)pp;
    const short8 p1 = *(const short8*)(pp + 8);
    #pragma unroll
    for (int j = 0; j < 8; ++j) {
      a[j]     += bf2f((unsigned short)p0[j]);
      a[j + 8] += bf2f((unsigned short)p1[j]);
    }
  }
  float* yp = y + (size_t)(row0 + r) * H_SZ + c0;
  #pragma unroll
  for (int q = 0; q < 4; ++q) {
    float4 o = {a[q * 4], a[q * 4 + 1], a[q * 4 + 2], a[q * 4 + 3]};
    *(float4*)(yp + q * 4) = o;
  }

  // ---- loss finalize (one thread of one block) ----
  if (blockIdx.x == 0 && tid == 0) {
    double si = 0.0, sl = 0.0;
    for (int e = 0; e < 16; ++e) { si += stats[e]; sl += stats[16 + e]; }
    const double mi = si / 16.0, mld = sl / 16.0;
    double vi = 0.0, vl = 0.0;
    for (int e = 0; e < 16; ++e) {
      const double di = stats[e] - mi;       vi += di * di;
      const double dl = stats[16 + e] - mld; vl += dl * dl;
    }
    vi /= 15.0; vl /= 15.0;  // ddof=1
    const double loss = 0.01 * (vi / (mi * mi + 1e-10) + vl / (mld * mld + 1e-10));
    y[(size_t)B_SZ * H_SZ] = (float)loss;
  }
}

extern "C" void kernel_launch(void* const* d_in, const int* in_sizes, int n_in,
                              void* d_out, int out_size, void* d_ws, size_t ws_size,
                              hipStream_t stream) {
  (void)in_sizes; (void)n_in; (void)out_size; (void)ws_size;
  const float* x    = (const float*)d_in[0];
  const float* wg   = (const float*)d_in[1];
  const float* wnoi = (const float*)d_in[2];
  const float* ew   = (const float*)d_in[3];
  const float* eb   = (const float*)d_in[4];
  const float* nz   = (const float*)d_in[5];
  float* y = (float*)d_out;

  char* ws = (char*)d_ws;
  const size_t MB = 1024 * 1024;
  unsigned short* xb     = (unsigned short*)(ws);                 // 16 MB
  unsigned short* wtb    = (unsigned short*)(ws + 16 * MB);       // 32 MB
  float* cl              = (float*)(ws + 48 * MB);                // 512 KB
  float* rn              = (float*)(ws + 48 * MB + 512 * 1024);   // 512 KB
  float* gates           = (float*)(ws + 49 * MB);                // 512 KB
  int*   rowidx          = (int*)  (ws + 49 * MB + 512 * 1024);   // 512 KB
  int*   rowmap          = (int*)  (ws + 50 * MB);                // 256 KB
  float* stats           = (float*)(ws + 50 * MB + 512 * 1024);   // 32 f32 + 16 counts
  unsigned short* partial= (unsigned short*)(ws + 52 * MB);       // ~143 MB

  hipLaunchKernelGGL(prep,        dim3(8448),          dim3(256), 0, stream,
                     x, wg, wnoi, ew, xb, wtb, cl, rn, stats);
  hipLaunchKernelGGL(gating_post, dim3(128),           dim3(64),  0, stream,
                     cl, rn, nz, gates, stats, rowidx, rowmap);
  hipLaunchKernelGGL(moe_gemm,    dim3(4 * MAXTILES),  dim3(512), 0, stream,
                     xb, wtb, gates, eb, stats, rowidx, partial);
  hipLaunchKernelGGL(reduce_k,    dim3(2048),          dim3(256), 0, stream,
                     partial, rowmap, stats, y);
}